// Round 1
// baseline (1838.723 us; speedup 1.0000x reference)
//
#include <hip/hip_runtime.h>
#include <hip/hip_bf16.h>

// Problem constants
#define B_   64
#define N_   8
#define F_   4096
#define H1_  1024
#define H2_  1024
#define OUT_ 512

using bf16x8 = __attribute__((ext_vector_type(8))) short;   // 8 bf16 = 4 VGPRs (MFMA A/B frag)
using f32x4  = __attribute__((ext_vector_type(4))) float;   // MFMA C/D frag

__device__ __forceinline__ short bf16rne(float v) {
    unsigned u = __builtin_bit_cast(unsigned, v);
    u += 0x7fffu + ((u >> 16) & 1u);
    return (short)(u >> 16);
}

// ---------------- prep kernels (run every call; outputs into d_ws) ----------------

// w0sum[o] = sum_c W0[o][c]  (layer0 collapses to scalar affine since all channels equal)
__global__ void prep_w0(const float* __restrict__ W0, float* __restrict__ w0sum) {
    int o = blockIdx.x * 256 + threadIdx.x;          // 1024 threads total
    float s = 0.f;
    #pragma unroll
    for (int c = 0; c < N_; ++c) s += W0[o * N_ + c];
    w0sum[o] = s;
}

// W1 (1024x1024 f32 row-major [o2][k]) -> bf16 fragment-block layout:
// block index = kb*1024 + o2 (kb = k>>3), each block = 8 contiguous bf16 (k..k+7 of row o2)
__global__ void prep_w1(const float* __restrict__ W1, short* __restrict__ w1f) {
    int t = blockIdx.x * 256 + threadIdx.x;          // 131072 blocks
    int kb = t >> 10, o2 = t & 1023;
    const float* src = W1 + o2 * 1024 + kb * 8;
    short* dst = w1f + (size_t)t * 8;
    #pragma unroll
    for (int j = 0; j < 8; ++j) dst[j] = bf16rne(src[j]);
}

// W2 (512x1024 f32 [o3][k2]) -> block index = k2b*512 + o3
__global__ void prep_w2(const float* __restrict__ W2, short* __restrict__ w2f) {
    int t = blockIdx.x * 256 + threadIdx.x;          // 65536 blocks
    int k2b = t >> 9, o3 = t & 511;
    const float* src = W2 + o3 * 1024 + k2b * 8;
    short* dst = w2f + (size_t)t * 8;
    #pragma unroll
    for (int j = 0; j < 8; ++j) dst[j] = bf16rne(src[j]);
}

// ---------------- fused main kernel ----------------
// Grid: 4096 WGs = (b 0..63) x (f-tile 0..63, 64 f each). 512 threads = 8 waves.
// Layer1: C1 = W1(1024x1024) x h1(1024 x 64f), o2-blocks of 512, wave owns 64(o2) x 64(f).
// Layer2: out = W2(512x1024) x h2, wave owns 64(o3) x 64(f), accumulated across o2-blocks.
__launch_bounds__(512, 2)
__global__ void fused_main(const float* __restrict__ x,
                           const float* __restrict__ b0,
                           const float* __restrict__ b1,
                           const float* __restrict__ b2,
                           const float* __restrict__ w0sum,
                           const short* __restrict__ w1f,
                           const short* __restrict__ w2f,
                           float* __restrict__ out) {
    __shared__ float  t_lds[64];
    __shared__ bf16x8 h1c[16 * 64];   // [kb 0..15][f 0..63], 128 k-chunk of h1, 16 KB
    __shared__ bf16x8 h2c[16 * 64];   // [kb2 0..15][f 0..63], 128 k2-chunk of h2, 16 KB

    const int tid  = threadIdx.x;
    const int wg   = blockIdx.x;
    const int b    = wg >> 6;
    const int fbase = (wg & 63) * 64;

    const int lane = tid & 63;
    const int ow   = tid >> 6;        // wave id 0..7
    const int q    = (tid >> 4) & 3;  // quad within wave
    const int n    = tid & 15;        // lane&15: col (B/D n-index, A m-index)

    // ---- t[f] = mean over N of x[b][:][fbase+f] ----
    if (tid < 64) {
        const float* xp = x + (size_t)b * N_ * F_ + fbase + tid;
        float s = 0.f;
        #pragma unroll
        for (int c = 0; c < N_; ++c) s += xp[c * F_];
        t_lds[tid] = s * (1.0f / N_);
    }
    __syncthreads();
    const float t_f = t_lds[tid & 63]; // each thread's f for h1 regen (f = tid&63 both rounds)

    f32x4 acc_out[16];                 // [ms(o3) * 4 + fs] 64 f32
    #pragma unroll
    for (int i = 0; i < 16; ++i) acc_out[i] = (f32x4){0.f, 0.f, 0.f, 0.f};

    for (int o2b = 0; o2b < 2; ++o2b) {
        f32x4 acc1[16];                // [ms(o2) * 4 + fs]
        #pragma unroll
        for (int i = 0; i < 16; ++i) acc1[i] = (f32x4){0.f, 0.f, 0.f, 0.f};

        // ---------- layer 1: K loop over 1024 in 8 chunks of 128 ----------
        for (int kc = 0; kc < 8; ++kc) {
            __syncthreads();           // previous h1c readers done
            // regenerate h1 chunk: h1[k] = relu(w0sum[k]*t + b0[k]), k in [kc*128, +128)
            #pragma unroll
            for (int r = 0; r < 2; ++r) {
                int blk = r * 512 + tid;       // = kb*64 + f
                int kb  = blk >> 6;
                int k0  = kc * 128 + kb * 8;
                float4 wa = *(const float4*)(w0sum + k0);
                float4 wb = *(const float4*)(w0sum + k0 + 4);
                float4 ba = *(const float4*)(b0 + k0);
                float4 bb = *(const float4*)(b0 + k0 + 4);
                bf16x8 pk;
                pk[0] = bf16rne(fmaxf(wa.x * t_f + ba.x, 0.f));
                pk[1] = bf16rne(fmaxf(wa.y * t_f + ba.y, 0.f));
                pk[2] = bf16rne(fmaxf(wa.z * t_f + ba.z, 0.f));
                pk[3] = bf16rne(fmaxf(wa.w * t_f + ba.w, 0.f));
                pk[4] = bf16rne(fmaxf(wb.x * t_f + bb.x, 0.f));
                pk[5] = bf16rne(fmaxf(wb.y * t_f + bb.y, 0.f));
                pk[6] = bf16rne(fmaxf(wb.z * t_f + bb.z, 0.f));
                pk[7] = bf16rne(fmaxf(wb.w * t_f + bb.w, 0.f));
                h1c[blk] = pk;
            }
            __syncthreads();

            #pragma unroll
            for (int kt = 0; kt < 4; ++kt) {   // 4 k-tiles of 32 per chunk
                const int kbglob = kc * 16 + kt * 4 + q;        // (global k)>>3 for this quad
                const int o2base = o2b * 512 + ow * 64;
                bf16x8 afr[4], bfr[4];
                #pragma unroll
                for (int ms = 0; ms < 4; ++ms)
                    afr[ms] = *(const bf16x8*)(w1f + ((size_t)kbglob * 1024 + o2base + ms * 16 + n) * 8);
                #pragma unroll
                for (int fs = 0; fs < 4; ++fs)
                    bfr[fs] = h1c[(kt * 4 + q) * 64 + fs * 16 + n];
                #pragma unroll
                for (int ms = 0; ms < 4; ++ms)
                    #pragma unroll
                    for (int fs = 0; fs < 4; ++fs)
                        acc1[ms * 4 + fs] = __builtin_amdgcn_mfma_f32_16x16x32_bf16(
                            afr[ms], bfr[fs], acc1[ms * 4 + fs], 0, 0, 0);
            }
        }

        // ---------- layer 2 partial: consume this o2-block (512 k2) in 4 chunks of 128 ----------
        for (int sc = 0; sc < 4; ++sc) {
            __syncthreads();           // previous h2c readers done
            if ((ow >> 1) == sc) {
                // waves 2sc, 2sc+1 stage their 64 o2-rows: h2 = relu(acc1 + b1), bf16 pack
                #pragma unroll
                for (int ms = 0; ms < 4; ++ms) {
                    const int o2loc  = ow * 64 + ms * 16 + q * 4;       // rows q*4+r
                    const int o2glob = o2b * 512 + o2loc;
                    float4 bv = *(const float4*)(b1 + o2glob);
                    const int kb2  = (ow & 1) * 8 + ms * 2 + (q >> 1);  // chunk-local k2>>3
                    const int half = q & 1;
                    #pragma unroll
                    for (int fs = 0; fs < 4; ++fs) {
                        f32x4 v = acc1[ms * 4 + fs];
                        uint2 pr;
                        pr.x = (unsigned short)bf16rne(fmaxf(v[0] + bv.x, 0.f))
                             | ((unsigned)(unsigned short)bf16rne(fmaxf(v[1] + bv.y, 0.f)) << 16);
                        pr.y = (unsigned short)bf16rne(fmaxf(v[2] + bv.z, 0.f))
                             | ((unsigned)(unsigned short)bf16rne(fmaxf(v[3] + bv.w, 0.f)) << 16);
                        *(uint2*)((char*)&h2c[kb2 * 64 + fs * 16 + n] + half * 8) = pr;
                    }
                }
            }
            __syncthreads();

            #pragma unroll
            for (int kt = 0; kt < 4; ++kt) {
                const int k2glob = o2b * 512 + sc * 128 + kt * 32 + q * 8;
                const size_t k2b = (size_t)(k2glob >> 3);
                bf16x8 afr[4], bfr[4];
                #pragma unroll
                for (int ms = 0; ms < 4; ++ms)
                    afr[ms] = *(const bf16x8*)(w2f + (k2b * 512 + ow * 64 + ms * 16 + n) * 8);
                #pragma unroll
                for (int fs = 0; fs < 4; ++fs)
                    bfr[fs] = h2c[(kt * 4 + q) * 64 + fs * 16 + n];
                #pragma unroll
                for (int ms = 0; ms < 4; ++ms)
                    #pragma unroll
                    for (int fs = 0; fs < 4; ++fs)
                        acc_out[ms * 4 + fs] = __builtin_amdgcn_mfma_f32_16x16x32_bf16(
                            afr[ms], bfr[fs], acc_out[ms * 4 + fs], 0, 0, 0);
            }
        }
    }

    // ---------- epilogue: out[b][o3][fbase+f] = acc_out + b2[o3] ----------
    #pragma unroll
    for (int ms = 0; ms < 4; ++ms) {
        const int o3base = ow * 64 + ms * 16 + q * 4;   // rows q*4 + r
        float4 bv = *(const float4*)(b2 + o3base);
        #pragma unroll
        for (int fs = 0; fs < 4; ++fs) {
            f32x4 v = acc_out[ms * 4 + fs];
            float* p = out + ((size_t)b * OUT_ + o3base) * F_ + fbase + fs * 16 + n;
            p[0 * F_] = v[0] + bv.x;
            p[1 * F_] = v[1] + bv.y;
            p[2 * F_] = v[2] + bv.z;
            p[3 * F_] = v[3] + bv.w;
        }
    }
}

// ---------------- launch ----------------
extern "C" void kernel_launch(void* const* d_in, const int* in_sizes, int n_in,
                              void* d_out, int out_size, void* d_ws, size_t ws_size,
                              hipStream_t stream) {
    (void)in_sizes; (void)n_in; (void)out_size; (void)ws_size;
    const float* x  = (const float*)d_in[0];
    const float* W0 = (const float*)d_in[1];
    const float* b0 = (const float*)d_in[2];
    const float* W1 = (const float*)d_in[3];
    const float* b1 = (const float*)d_in[4];
    const float* W2 = (const float*)d_in[5];
    const float* b2 = (const float*)d_in[6];
    float* out = (float*)d_out;

    char* ws = (char*)d_ws;
    short* w1f   = (short*)ws;                       // 2 MB  (1024x1024 bf16, frag-block)
    short* w2f   = (short*)(ws + (2u << 20));        // 1 MB  (512x1024 bf16, frag-block)
    float* w0sum = (float*)(ws + (3u << 20));        // 4 KB

    prep_w1<<<512, 256, 0, stream>>>(W1, w1f);
    prep_w2<<<256, 256, 0, stream>>>(W2, w2f);
    prep_w0<<<4, 256, 0, stream>>>(W0, w0sum);
    fused_main<<<4096, 512, 0, stream>>>(x, b0, b1, b2, w0sum, w1f, w2f, out);
}